// Round 9
// baseline (207.749 us; speedup 1.0000x reference)
//
#include <hip/hip_runtime.h>

// CombinedLoss: chamfer(pred,gt) + 0.1*repulsion(pred,k=4) + 0.01*(1 - mean(n_pred . n_gt))
// B=8, N=2048, fp32 in, fp32 scalar out.
// Normals match np.linalg.eigh (LAPACK ssyevd) signs point-by-point via faithful
// fp32 ssytd2+ssteqr+sormtr emulation (R3-R8: absmax 0.0).
// R9: candidates are WAVE-UNIFORM -> stream them through the scalar pipe
// (readfirstlane + s_load_dwordx4 from pre-packed float4 arrays) instead of
// LDS broadcast. Kills the LDS staging (64KB->22KB), the 2 ds_read_b128/iter,
// and the __syncthreads in the hot path; occupancy ~8 waves/SIMD; VALU-issue
// becomes the floor. Selection math untouched -> bit-identical.

#define NB 8
#define NP 2048
#define KW 10     // per-slice kept keys
#define KN 16

// ---------------- LAPACK helpers (fp32, faithful — DO NOT TOUCH) ----------------

__device__ __forceinline__ float f_slapy2(float x, float y) {
    float xa = fabsf(x), ya = fabsf(y);
    float w = fmaxf(xa, ya), zm = fminf(xa, ya);
    if (zm == 0.f) return w;
    float q = zm / w;
    return w * sqrtf(1.f + q * q);
}

// LAPACK >=3.10 slartg convention: c >= 0 always.
__device__ __forceinline__ void f_slartg(float f, float g, float* cs, float* sn, float* r) {
    if (g == 0.f) { *cs = 1.f; *sn = 0.f; *r = f; }
    else if (f == 0.f) { *cs = 0.f; *sn = copysignf(1.f, g); *r = fabsf(g); }
    else {
        float d = sqrtf(__fadd_rn(__fmul_rn(f, f), __fmul_rn(g, g)));
        *cs = fabsf(f) / d;
        *r  = copysignf(d, f);
        *sn = g / *r;
    }
}

__device__ void f_slaev2(float a, float b, float c,
                         float* rt1, float* rt2, float* cs1, float* sn1) {
    float sm = a + c;
    float df = a - c;
    float adf = fabsf(df);
    float tb = b + b;
    float ab = fabsf(tb);
    float acmx, acmn;
    if (fabsf(a) > fabsf(c)) { acmx = a; acmn = c; } else { acmx = c; acmn = a; }
    float rt;
    if (adf > ab)      { float q = ab / adf; rt = adf * sqrtf(1.f + q * q); }
    else if (adf < ab) { float q = adf / ab; rt = ab * sqrtf(1.f + q * q); }
    else               rt = ab * sqrtf(2.f);
    int sgn1;
    if (sm < 0.f) {
        *rt1 = 0.5f * (sm - rt); sgn1 = -1;
        *rt2 = (acmx / *rt1) * acmn - (b / *rt1) * b;
    } else if (sm > 0.f) {
        *rt1 = 0.5f * (sm + rt); sgn1 = 1;
        *rt2 = (acmx / *rt1) * acmn - (b / *rt1) * b;
    } else {
        *rt1 = 0.5f * rt; *rt2 = -0.5f * rt; sgn1 = 1;
    }
    float cs; int sgn2;
    if (df >= 0.f) { cs = df + rt; sgn2 = 1; }
    else           { cs = df - rt; sgn2 = -1; }
    float acs = fabsf(cs);
    if (acs > ab) {
        float ct = -tb / cs;
        *sn1 = 1.f / sqrtf(1.f + ct * ct);
        *cs1 = ct * *sn1;
    } else {
        if (ab == 0.f) { *cs1 = 1.f; *sn1 = 0.f; }
        else {
            float tn = -cs / tb;
            *cs1 = 1.f / sqrtf(1.f + tn * tn);
            *sn1 = tn * *cs1;
        }
    }
    if (sgn1 == sgn2) { float tn = *cs1; *cs1 = -*sn1; *sn1 = tn; }
}

// fp32 ssyevd for a 3x3 symmetric matrix (lower triangle given), returns
// eigenvector of the SMALLEST eigenvalue, with LAPACK's sign convention.
__device__ void ssyevd3_evec0(float a00, float a10, float a20,
                              float a11, float a21, float a22,
                              float* ox, float* oy, float* oz) {
    // ---- ssytd2('L') ----
    float d[3], e[2];
    float tau = 0.f, v2 = 0.f;
    float xnorm = fabsf(a20);
    if (xnorm == 0.f) {
        tau = 0.f;
        d[0] = a00; d[1] = a11; d[2] = a22; e[0] = a10; e[1] = a21;
    } else {
        float beta = -copysignf(f_slapy2(a10, xnorm), a10);
        tau = (beta - a10) / beta;
        float inv = 1.f / (a10 - beta);
        v2 = a20 * inv;
        float x1 = tau * (a11 + a21 * v2);
        float x2 = tau * (a21 + a22 * v2);
        float alpha = -0.5f * tau * (x1 + x2 * v2);
        float w1 = x1 + alpha;
        float w2 = x2 + alpha * v2;
        float b11 = a11 - 2.f * w1;
        float b21 = a21 - v2 * w1 - w2;
        float b22 = a22 - 2.f * (v2 * w2);
        d[0] = a00; d[1] = b11; d[2] = b22; e[0] = beta; e[1] = b21;
    }
    // ---- ssteqr('I', n=3) ----
    const float eps    = 5.9604645e-08f;
    const float eps2   = eps * eps;
    const float safmin = 1.1754944e-38f;
    const float ssfmax = sqrtf(1.f / safmin) / 3.f;
    const float ssfmin = sqrtf(safmin) / eps2;
    const int n = 3, nmaxit = 90;
    float z[3][3] = {{1.f,0.f,0.f},{0.f,1.f,0.f},{0.f,0.f,1.f}};
    int jtot = 0;
    int l1 = 1;

    while (true) {
        if (l1 > n) break;
        if (l1 > 1) e[l1 - 2] = 0.f;
        int m = n;
        for (int mi = l1; mi <= n - 1; ++mi) {
            float tst = fabsf(e[mi - 1]);
            if (tst == 0.f) { m = mi; break; }
            if (tst <= (sqrtf(fabsf(d[mi - 1])) * sqrtf(fabsf(d[mi]))) * eps) {
                e[mi - 1] = 0.f; m = mi; break;
            }
        }
        int l = l1, lsv = l, lend = m, lendsv = lend;
        l1 = m + 1;
        if (lend == l) continue;

        float anorm = 0.f;
        for (int i = l; i <= lend; ++i) anorm = fmaxf(anorm, fabsf(d[i - 1]));
        for (int i = l; i <= lend - 1; ++i) anorm = fmaxf(anorm, fabsf(e[i - 1]));
        int iscale = 0; float sclto = 1.f;
        if (anorm == 0.f) continue;
        if (anorm > ssfmax) { iscale = 1; sclto = ssfmax; }
        else if (anorm < ssfmin) { iscale = 2; sclto = ssfmin; }
        if (iscale) {
            float mul = sclto / anorm;
            for (int i = l; i <= lend; ++i) d[i - 1] *= mul;
            for (int i = l; i <= lend - 1; ++i) e[i - 1] *= mul;
        }
        if (fabsf(d[lend - 1]) < fabsf(d[l - 1])) { lend = lsv; l = lendsv; }

        if (lend > l) {
            // QL
            while (true) {
                int mq = lend;
                if (l != lend) {
                    for (int i = l; i <= lend - 1; ++i) {
                        float ei = e[i - 1];
                        float tst = ei * ei;
                        if (tst <= (eps2 * fabsf(d[i - 1])) * fabsf(d[i]) + safmin) { mq = i; break; }
                    }
                }
                if (mq < lend) e[mq - 1] = 0.f;
                float p = d[l - 1];
                if (mq == l) { d[l - 1] = p; l = l + 1; if (l <= lend) continue; break; }
                if (mq == l + 1) {
                    float rt1, rt2, c, s;
                    f_slaev2(d[l - 1], e[l - 1], d[l], &rt1, &rt2, &c, &s);
                    for (int i = 0; i < 3; ++i) {
                        float temp = z[i][l];
                        z[i][l]     = c * temp - s * z[i][l - 1];
                        z[i][l - 1] = s * temp + c * z[i][l - 1];
                    }
                    d[l - 1] = rt1; d[l] = rt2; e[l - 1] = 0.f;
                    l += 2; if (l <= lend) continue; break;
                }
                if (jtot == nmaxit) break;
                jtot++;
                float g = (d[l] - p) / (2.f * e[l - 1]);
                float r = f_slapy2(g, 1.f);
                g = d[mq - 1] - p + e[l - 1] / (g + copysignf(r, g));
                float s = 1.f, c = 1.f; p = 0.f;
                float cw[2], sw[2];
                for (int i = mq - 1; i >= l; --i) {
                    float f = s * e[i - 1];
                    float b = c * e[i - 1];
                    f_slartg(g, f, &c, &s, &r);
                    if (i != mq - 1) e[i] = r;
                    g = d[i] - p;
                    r = (d[i - 1] - g) * s + 2.f * c * b;
                    p = s * r;
                    d[i] = g + p;
                    g = c * r - b;
                    cw[i - l] = c; sw[i - l] = -s;
                }
                for (int j = mq - l; j >= 1; --j) {
                    float cj = cw[j - 1], sj = sw[j - 1];
                    int c0 = l - 1 + (j - 1);
                    for (int i = 0; i < 3; ++i) {
                        float temp = z[i][c0 + 1];
                        z[i][c0 + 1] = cj * temp - sj * z[i][c0];
                        z[i][c0]     = sj * temp + cj * z[i][c0];
                    }
                }
                d[l - 1] -= p;
                e[l - 1] = g;
            }
        } else {
            // QR
            while (true) {
                int mq = lend;
                if (l != lend) {
                    for (int i = l; i >= lend + 1; --i) {
                        float ei = e[i - 2];
                        float tst = ei * ei;
                        if (tst <= (eps2 * fabsf(d[i - 1])) * fabsf(d[i - 2]) + safmin) { mq = i; break; }
                    }
                }
                if (mq > lend) e[mq - 2] = 0.f;
                float p = d[l - 1];
                if (mq == l) { d[l - 1] = p; l = l - 1; if (l >= lend) continue; break; }
                if (mq == l - 1) {
                    float rt1, rt2, c, s;
                    f_slaev2(d[l - 2], e[l - 2], d[l - 1], &rt1, &rt2, &c, &s);
                    for (int i = 0; i < 3; ++i) {
                        float temp = z[i][l - 1];
                        z[i][l - 1] = c * temp - s * z[i][l - 2];
                        z[i][l - 2] = s * temp + c * z[i][l - 2];
                    }
                    d[l - 2] = rt1; d[l - 1] = rt2; e[l - 2] = 0.f;
                    l -= 2; if (l >= lend) continue; break;
                }
                if (jtot == nmaxit) break;
                jtot++;
                float g = (d[l - 2] - p) / (2.f * e[l - 2]);
                float r = f_slapy2(g, 1.f);
                g = d[mq - 1] - p + e[l - 2] / (g + copysignf(r, g));
                float s = 1.f, c = 1.f; p = 0.f;
                float cw[2], sw[2];
                for (int i = mq; i <= l - 1; ++i) {
                    float f = s * e[i - 1];
                    float b = c * e[i - 1];
                    f_slartg(g, f, &c, &s, &r);
                    if (i != mq) e[i - 2] = r;
                    g = d[i - 1] - p;
                    r = (d[i] - g) * s + 2.f * c * b;
                    p = s * r;
                    d[i - 1] = g + p;
                    g = c * r - b;
                    cw[i - mq] = c; sw[i - mq] = s;
                }
                for (int j = 1; j <= l - mq; ++j) {
                    float cj = cw[j - 1], sj = sw[j - 1];
                    int c0 = mq - 1 + (j - 1);
                    for (int i = 0; i < 3; ++i) {
                        float temp = z[i][c0 + 1];
                        z[i][c0 + 1] = cj * temp - sj * z[i][c0];
                        z[i][c0]     = sj * temp + cj * z[i][c0];
                    }
                }
                d[l - 1] -= p;
                e[l - 2] = g;
            }
        }
        if (iscale) {
            float mul = anorm / sclto;
            for (int i = lsv; i <= lendsv; ++i) d[i - 1] *= mul;
            for (int i = lsv; i <= lendsv - 1; ++i) e[i - 1] *= mul;
        }
        if (jtot >= nmaxit) break;
    }

    // sort ascending (column swaps — no sign change)
    for (int ii = 2; ii <= 3; ++ii) {
        int i = ii - 1, k = i;
        float p = d[i - 1];
        for (int j = ii; j <= 3; ++j) if (d[j - 1] < p) { k = j; p = d[j - 1]; }
        if (k != i) {
            d[k - 1] = d[i - 1]; d[i - 1] = p;
            for (int r = 0; r < 3; ++r) { float t = z[r][i - 1]; z[r][i - 1] = z[r][k - 1]; z[r][k - 1] = t; }
        }
    }
    // sormtr('L','L','N')
    float r0 = z[0][0], r1 = z[1][0], r2 = z[2][0];
    if (tau != 0.f) {
        float sum = r1 + v2 * r2;
        r1 -= tau * sum;
        r2 -= tau * (v2 * sum);
    }
    *ox = r0; *oy = r1; *oz = r2;
}

// ---------------- common ----------------

__device__ __forceinline__ float dot_rn(float ax, float ay, float az,
                                        float bx, float by, float bz) {
    return __fadd_rn(__fadd_rn(__fmul_rn(ax, bx), __fmul_rn(ay, by)), __fmul_rn(az, bz));
}

// Branchless sorted-chain inserts: keys ascending; drops the largest.
__device__ __forceinline__ void chain10(unsigned k[KW], unsigned x) {
    unsigned t = x;
    #pragma unroll
    for (int s = 0; s < KW; ++s) {
        unsigned a = k[s];
        unsigned lo = a < t ? a : t;     // v_min_u32
        unsigned hi = a < t ? t : a;     // v_max_u32
        k[s] = lo; t = hi;
    }
}
__device__ __forceinline__ void chain16(unsigned k[KN], unsigned x) {
    unsigned t = x;
    #pragma unroll
    for (int s = 0; s < KN; ++s) {
        unsigned a = k[s];
        unsigned lo = a < t ? a : t;
        unsigned hi = a < t ? t : a;
        k[s] = lo; t = hi;
    }
}

// ---------------- repack kernel ----------------
// Build float4 (x,y,z,|p|^2) arrays for scalar-broadcast loads, |p|^2 via the
// reference-exact dot form.
__global__ __launch_bounds__(256) void repack_kernel(
    const float* __restrict__ pred, const float* __restrict__ gt,
    float4* __restrict__ p4, float4* __restrict__ g4)
{
    int i = blockIdx.x * 256 + threadIdx.x;       // 0 .. 2*NB*NP-1
    int half = NB * NP;
    const float* src = (i < half) ? pred : gt;
    int k = (i < half) ? i : i - half;
    float x = src[3 * k], y = src[3 * k + 1], z = src[3 * k + 2];
    float4 v = make_float4(x, y, z, dot_rn(x, y, z, x, y, z));
    ((i < half) ? p4 : g4)[k] = v;
}

// ---------------- scan kernel ----------------
// 512 blocks x 512 threads (8 waves). Block = tile of 64 queries. Wave w scans
// interleaved slice j = 8t+w; candidate fetched via SCALAR load (jj is
// wave-uniform: readfirstlane). Branchless sorted top-10 per slice; exact
// top-16 via 8x10 merge + violation-detect + rare slice rescan (P~2.6e-7).
// Keys: (d2bits & ~0x7FF) | j, reference-exact d2 -> selection bit-identical.
#define KIDX(s, w, l) (((s) * 8 + (w)) * 64 + (l))

__global__ __launch_bounds__(512) void scan_kernel(
    const float* __restrict__ pred, const float* __restrict__ gt,
    const float4* __restrict__ p4, const float4* __restrict__ g4,
    float4* __restrict__ nP4, float4* __restrict__ nG4, double* __restrict__ acc)
{
    __shared__ unsigned kbuf[KW * 8 * 64];   // 20 KB
    __shared__ float mbuf[8 * 64];           // 2 KB
    float* cache = (float*)kbuf;             // tail alias (wave0-sequential only)

    int bi = blockIdx.x;
    bool predHome = bi < NB * 32;
    int lb = predHome ? bi : bi - NB * 32;
    int b = lb >> 5;
    int tile = lb & 31;
    int tid  = threadIdx.x;
    int wave = tid >> 6;
    int lane = tid & 63;

    const float*  home   = (predHome ? pred : gt) + (size_t)b * NP * 3;
    const float4* home4  = (predHome ? p4 : g4) + (size_t)b * NP;
    const float4* other4 = (predHome ? g4 : p4) + (size_t)b * NP;

    int wv = __builtin_amdgcn_readfirstlane(wave);   // wave id in SGPR

    int im = tile * 64 + lane;              // original index of this query
    float4 q = home4[im];                   // per-lane coalesced vector load
    float qx = q.x, qy = q.y, qz = q.z, qq = q.w;

    unsigned keys[KW];
    #pragma unroll
    for (int s = 0; s < KW; ++s) keys[s] = 0x7F800000u | (unsigned)s;  // sorted inf seeds

    float minv = 1e30f;

    for (int t = 0; t < NP / 8; ++t) {
        int jj = (t << 3) | wv;                                // scalar index
        float4 h = home4[jj];                                  // s_load_dwordx4
        float dotj = dot_rn(qx, qy, qz, h.x, h.y, h.z);
        float d2 = __fsub_rn(__fadd_rn(qq, h.w), __fmul_rn(2.f, dotj));
        chain10(keys, (__float_as_uint(d2) & 0xFFFFF800u) | (unsigned)jj);
        float4 o = other4[jj];                                 // s_load_dwordx4
        float ex = qx - o.x, ey = qy - o.y, ez = qz - o.z;
        minv = fminf(minv, fmaf(ex, ex, fmaf(ey, ey, ez * ez)));
    }

    // publish per-wave sorted top-10 + chamfer partial min
    #pragma unroll
    for (int s = 0; s < KW; ++s) kbuf[KIDX(s, wave, lane)] = keys[s];
    mbuf[wave * 64 + lane] = minv;
    __syncthreads();

    if (wave != 0) return;

    // --- merge 8x10 -> sorted top-16 ---
    unsigned k16[KN];
    #pragma unroll
    for (int s = 0; s < KW; ++s) k16[s] = keys[s];             // own sorted 10
    #pragma unroll
    for (int s = KW; s < KN; ++s) k16[s] = 0x7F800000u | (unsigned)s;  // seeds (> any real)
    for (int w = 1; w < 8; ++w) {
        #pragma unroll
        for (int s = 0; s < KW; ++s) chain16(k16, kbuf[KIDX(s, w, lane)]);
    }
    minv = fminf(fminf(fminf(mbuf[lane], mbuf[64 + lane]),
                       fminf(mbuf[128 + lane], mbuf[192 + lane])),
                 fminf(fminf(mbuf[256 + lane], mbuf[320 + lane]),
                       fminf(mbuf[384 + lane], mbuf[448 + lane])));

    // --- violation detect: slice may hide a top-16 member iff its 10th-best
    //     (sorted slot 9) < pool 16th (k16[15]). Exact repair below. ---
    unsigned flags = 0;
    #pragma unroll
    for (int w = 0; w < 8; ++w)
        flags |= (kbuf[KIDX(KW - 1, w, lane)] < k16[15]) ? (1u << w) : 0u;

    if (__any(flags != 0)) {                 // ~0.07 expected events per LAUNCH
        #pragma unroll
        for (int s = 0; s < KN; ++s)
            k16[s] = flags ? (0x7F800000u | (unsigned)s) : k16[s];   // reinit flagged lanes
        for (int w = 0; w < 8; ++w) {
            #pragma unroll
            for (int s = 0; s < KW; ++s) {
                unsigned kk = kbuf[KIDX(s, w, lane)];
                bool use = (flags != 0) && !((flags >> w) & 1);
                chain16(k16, use ? kk : 0xFFFFFFFFu);          // inf = no-op
            }
        }
        for (int w = 0; w < 8; ++w) {
            if (__any((flags >> w) & 1)) {
                bool actw = ((flags >> w) & 1) != 0;
                for (int t = 0; t < NP / 8; ++t) {
                    int jj = (t << 3) | w;
                    float4 h = home4[jj];
                    float dotj = dot_rn(qx, qy, qz, h.x, h.y, h.z);
                    float d2 = __fsub_rn(__fadd_rn(qq, h.w), __fmul_rn(2.f, dotj));
                    unsigned key = (__float_as_uint(d2) & 0xFFFFF800u) | (unsigned)jj;
                    chain16(k16, actw ? key : 0xFFFFFFFFu);
                }
            }
        }
    }

    // --- repulsion: k16 sorted ascending, slot 0 = self (d2=0) -> slots 1..4 ---
    float rep = 0.0f;
    if (predHome) {
        #pragma unroll
        for (int r = 1; r <= 4; ++r) {
            float d2 = __uint_as_float(k16[r] & 0xFFFFF800u);
            float dd = sqrtf(fmaxf(d2, 1e-12f));
            rep += fmaxf(0.02f - dd, 0.0f);
        }
    }

    // --- covariance over the 16-NN (gather by index from global, L2-hot) ---
    float sx = 0.f, sy = 0.f, sz = 0.f;
    #pragma unroll
    for (int s = 0; s < KN; ++s) {
        const float* hp = home + 3 * (size_t)(k16[s] & 0x7FFu);
        float px = hp[0], py = hp[1], pz = hp[2];
        cache[(s * 3 + 0) * 64 + lane] = px;
        cache[(s * 3 + 1) * 64 + lane] = py;
        cache[(s * 3 + 2) * 64 + lane] = pz;
        sx += px; sy += py; sz += pz;
    }
    float mx = sx * (1.0f / KN), my = sy * (1.0f / KN), mz = sz * (1.0f / KN);
    float cxx = 0.f, cxy = 0.f, cxz = 0.f, cyy = 0.f, cyz = 0.f, czz = 0.f;
    #pragma unroll
    for (int s = 0; s < KN; ++s) {
        float ax = cache[(s * 3 + 0) * 64 + lane] - mx;
        float ay = cache[(s * 3 + 1) * 64 + lane] - my;
        float az = cache[(s * 3 + 2) * 64 + lane] - mz;
        cxx += ax * ax; cxy += ax * ay; cxz += ax * az;
        cyy += ay * ay; cyz += ay * az; czz += az * az;
    }
    cxx *= (1.f / KN); cxy *= (1.f / KN); cxz *= (1.f / KN);
    cyy *= (1.f / KN); cyz *= (1.f / KN); czz *= (1.f / KN);

    // --- normal via faithful ssyevd emulation ---
    float nx, ny, nz;
    ssyevd3_evec0(cxx, cxy, cxz, cyy, cyz, czz, &nx, &ny, &nz);

    int gi = b * NP + im;
    (predHome ? nP4 : nG4)[gi] = make_float4(nx, ny, nz, 0.f);

    double part = (double)minv * (1.0 / (NB * NP))
                + (double)rep  * (0.1 / (NB * NP * 4));

    #pragma unroll
    for (int off = 32; off > 0; off >>= 1) part += __shfl_down(part, off);
    if (lane == 0) atomicAdd(acc, part);
}

// ---------------------------------------------------------------------------
// Fused normal-dot + finalize: single block, runs after scan (stream order).
__global__ __launch_bounds__(1024) void dotfin_kernel(
    const float4* __restrict__ nP4, const float4* __restrict__ nG4,
    const double* __restrict__ acc, float* __restrict__ out)
{
    int tid = threadIdx.x;
    float s = 0.f;
    for (int i = tid; i < NB * NP; i += 1024) {
        float4 a = nP4[i], c = nG4[i];
        s += a.x * c.x + a.y * c.y + a.z * c.z;
    }
    double part = (double)s;
    #pragma unroll
    for (int off = 32; off > 0; off >>= 1) part += __shfl_down(part, off);
    __shared__ double w[16];
    if ((tid & 63) == 0) w[tid >> 6] = part;
    __syncthreads();
    if (tid == 0) {
        double t = 0.0;
        for (int k = 0; k < 16; ++k) t += w[k];
        out[0] = (float)(acc[0] - t * (0.01 / (NB * NP)) + 0.01);
    }
}

// ---------------------------------------------------------------------------
extern "C" void kernel_launch(void* const* d_in, const int* in_sizes, int n_in,
                              void* d_out, int out_size, void* d_ws, size_t ws_size,
                              hipStream_t stream)
{
    const float* pred = (const float*)d_in[0];
    const float* gt   = (const float*)d_in[1];

    // ws layout: acc(64) | p4 (262144) | g4 (262144) | nP4 (262144) | nG4 (262144)
    char* base = (char*)d_ws;
    double* acc = (double*)base;
    float4* p4  = (float4*)(base + 64);
    float4* g4  = p4 + (size_t)NB * NP;
    float4* nP4 = g4 + (size_t)NB * NP;
    float4* nG4 = nP4 + (size_t)NB * NP;

    hipMemsetAsync(d_ws, 0, 64, stream);
    repack_kernel<<<dim3(2 * NB * NP / 256), dim3(256), 0, stream>>>(pred, gt, p4, g4);
    scan_kernel<<<dim3(NB * 32 * 2), dim3(512), 0, stream>>>(pred, gt, p4, g4, nP4, nG4, acc);
    dotfin_kernel<<<dim3(1), dim3(1024), 0, stream>>>(nP4, nG4, acc, (float*)d_out);
}

// Round 10
// 204.054 us; speedup vs baseline: 1.0181x; 1.0181x over previous
//
#include <hip/hip_runtime.h>

// CombinedLoss: chamfer(pred,gt) + 0.1*repulsion(pred,k=4) + 0.01*(1 - mean(n_pred . n_gt))
// B=8, N=2048, fp32 in, fp32 scalar out.
// Normals match np.linalg.eigh (LAPACK ssyevd) signs point-by-point via faithful
// fp32 ssytd2+ssteqr+sormtr emulation (R3-R9: absmax 0.0).
// R10: R8's LDS-broadcast scan (R9 scalar path regressed: K$ thrash) with
// (1) TWO queries per lane -> 2 independent chain10s per ds_read (the serial
// chain was the R8 limiter, not issue), grid 256 blocks = 1 block/CU;
// (2) tail (merge+eigensolve) distributed across all 8 waves (R8 ran it in
// wave 0 only); (3) fallback/cov gathers from global so kbuf aliases staging.
// Selection math unchanged -> bit-identical.

#define NB 8
#define NP 2048
#define KW 10     // per-slice kept keys
#define KN 16

// ---------------- LAPACK helpers (fp32, faithful — DO NOT TOUCH) ----------------

__device__ __forceinline__ float f_slapy2(float x, float y) {
    float xa = fabsf(x), ya = fabsf(y);
    float w = fmaxf(xa, ya), zm = fminf(xa, ya);
    if (zm == 0.f) return w;
    float q = zm / w;
    return w * sqrtf(1.f + q * q);
}

// LAPACK >=3.10 slartg convention: c >= 0 always.
__device__ __forceinline__ void f_slartg(float f, float g, float* cs, float* sn, float* r) {
    if (g == 0.f) { *cs = 1.f; *sn = 0.f; *r = f; }
    else if (f == 0.f) { *cs = 0.f; *sn = copysignf(1.f, g); *r = fabsf(g); }
    else {
        float d = sqrtf(__fadd_rn(__fmul_rn(f, f), __fmul_rn(g, g)));
        *cs = fabsf(f) / d;
        *r  = copysignf(d, f);
        *sn = g / *r;
    }
}

__device__ void f_slaev2(float a, float b, float c,
                         float* rt1, float* rt2, float* cs1, float* sn1) {
    float sm = a + c;
    float df = a - c;
    float adf = fabsf(df);
    float tb = b + b;
    float ab = fabsf(tb);
    float acmx, acmn;
    if (fabsf(a) > fabsf(c)) { acmx = a; acmn = c; } else { acmx = c; acmn = a; }
    float rt;
    if (adf > ab)      { float q = ab / adf; rt = adf * sqrtf(1.f + q * q); }
    else if (adf < ab) { float q = adf / ab; rt = ab * sqrtf(1.f + q * q); }
    else               rt = ab * sqrtf(2.f);
    int sgn1;
    if (sm < 0.f) {
        *rt1 = 0.5f * (sm - rt); sgn1 = -1;
        *rt2 = (acmx / *rt1) * acmn - (b / *rt1) * b;
    } else if (sm > 0.f) {
        *rt1 = 0.5f * (sm + rt); sgn1 = 1;
        *rt2 = (acmx / *rt1) * acmn - (b / *rt1) * b;
    } else {
        *rt1 = 0.5f * rt; *rt2 = -0.5f * rt; sgn1 = 1;
    }
    float cs; int sgn2;
    if (df >= 0.f) { cs = df + rt; sgn2 = 1; }
    else           { cs = df - rt; sgn2 = -1; }
    float acs = fabsf(cs);
    if (acs > ab) {
        float ct = -tb / cs;
        *sn1 = 1.f / sqrtf(1.f + ct * ct);
        *cs1 = ct * *sn1;
    } else {
        if (ab == 0.f) { *cs1 = 1.f; *sn1 = 0.f; }
        else {
            float tn = -cs / tb;
            *cs1 = 1.f / sqrtf(1.f + tn * tn);
            *sn1 = tn * *cs1;
        }
    }
    if (sgn1 == sgn2) { float tn = *cs1; *cs1 = -*sn1; *sn1 = tn; }
}

// fp32 ssyevd for a 3x3 symmetric matrix (lower triangle given), returns
// eigenvector of the SMALLEST eigenvalue, with LAPACK's sign convention.
__device__ void ssyevd3_evec0(float a00, float a10, float a20,
                              float a11, float a21, float a22,
                              float* ox, float* oy, float* oz) {
    // ---- ssytd2('L') ----
    float d[3], e[2];
    float tau = 0.f, v2 = 0.f;
    float xnorm = fabsf(a20);
    if (xnorm == 0.f) {
        tau = 0.f;
        d[0] = a00; d[1] = a11; d[2] = a22; e[0] = a10; e[1] = a21;
    } else {
        float beta = -copysignf(f_slapy2(a10, xnorm), a10);
        tau = (beta - a10) / beta;
        float inv = 1.f / (a10 - beta);
        v2 = a20 * inv;
        float x1 = tau * (a11 + a21 * v2);
        float x2 = tau * (a21 + a22 * v2);
        float alpha = -0.5f * tau * (x1 + x2 * v2);
        float w1 = x1 + alpha;
        float w2 = x2 + alpha * v2;
        float b11 = a11 - 2.f * w1;
        float b21 = a21 - v2 * w1 - w2;
        float b22 = a22 - 2.f * (v2 * w2);
        d[0] = a00; d[1] = b11; d[2] = b22; e[0] = beta; e[1] = b21;
    }
    // ---- ssteqr('I', n=3) ----
    const float eps    = 5.9604645e-08f;
    const float eps2   = eps * eps;
    const float safmin = 1.1754944e-38f;
    const float ssfmax = sqrtf(1.f / safmin) / 3.f;
    const float ssfmin = sqrtf(safmin) / eps2;
    const int n = 3, nmaxit = 90;
    float z[3][3] = {{1.f,0.f,0.f},{0.f,1.f,0.f},{0.f,0.f,1.f}};
    int jtot = 0;
    int l1 = 1;

    while (true) {
        if (l1 > n) break;
        if (l1 > 1) e[l1 - 2] = 0.f;
        int m = n;
        for (int mi = l1; mi <= n - 1; ++mi) {
            float tst = fabsf(e[mi - 1]);
            if (tst == 0.f) { m = mi; break; }
            if (tst <= (sqrtf(fabsf(d[mi - 1])) * sqrtf(fabsf(d[mi]))) * eps) {
                e[mi - 1] = 0.f; m = mi; break;
            }
        }
        int l = l1, lsv = l, lend = m, lendsv = lend;
        l1 = m + 1;
        if (lend == l) continue;

        float anorm = 0.f;
        for (int i = l; i <= lend; ++i) anorm = fmaxf(anorm, fabsf(d[i - 1]));
        for (int i = l; i <= lend - 1; ++i) anorm = fmaxf(anorm, fabsf(e[i - 1]));
        int iscale = 0; float sclto = 1.f;
        if (anorm == 0.f) continue;
        if (anorm > ssfmax) { iscale = 1; sclto = ssfmax; }
        else if (anorm < ssfmin) { iscale = 2; sclto = ssfmin; }
        if (iscale) {
            float mul = sclto / anorm;
            for (int i = l; i <= lend; ++i) d[i - 1] *= mul;
            for (int i = l; i <= lend - 1; ++i) e[i - 1] *= mul;
        }
        if (fabsf(d[lend - 1]) < fabsf(d[l - 1])) { lend = lsv; l = lendsv; }

        if (lend > l) {
            // QL
            while (true) {
                int mq = lend;
                if (l != lend) {
                    for (int i = l; i <= lend - 1; ++i) {
                        float ei = e[i - 1];
                        float tst = ei * ei;
                        if (tst <= (eps2 * fabsf(d[i - 1])) * fabsf(d[i]) + safmin) { mq = i; break; }
                    }
                }
                if (mq < lend) e[mq - 1] = 0.f;
                float p = d[l - 1];
                if (mq == l) { d[l - 1] = p; l = l + 1; if (l <= lend) continue; break; }
                if (mq == l + 1) {
                    float rt1, rt2, c, s;
                    f_slaev2(d[l - 1], e[l - 1], d[l], &rt1, &rt2, &c, &s);
                    for (int i = 0; i < 3; ++i) {
                        float temp = z[i][l];
                        z[i][l]     = c * temp - s * z[i][l - 1];
                        z[i][l - 1] = s * temp + c * z[i][l - 1];
                    }
                    d[l - 1] = rt1; d[l] = rt2; e[l - 1] = 0.f;
                    l += 2; if (l <= lend) continue; break;
                }
                if (jtot == nmaxit) break;
                jtot++;
                float g = (d[l] - p) / (2.f * e[l - 1]);
                float r = f_slapy2(g, 1.f);
                g = d[mq - 1] - p + e[l - 1] / (g + copysignf(r, g));
                float s = 1.f, c = 1.f; p = 0.f;
                float cw[2], sw[2];
                for (int i = mq - 1; i >= l; --i) {
                    float f = s * e[i - 1];
                    float b = c * e[i - 1];
                    f_slartg(g, f, &c, &s, &r);
                    if (i != mq - 1) e[i] = r;
                    g = d[i] - p;
                    r = (d[i - 1] - g) * s + 2.f * c * b;
                    p = s * r;
                    d[i] = g + p;
                    g = c * r - b;
                    cw[i - l] = c; sw[i - l] = -s;
                }
                for (int j = mq - l; j >= 1; --j) {
                    float cj = cw[j - 1], sj = sw[j - 1];
                    int c0 = l - 1 + (j - 1);
                    for (int i = 0; i < 3; ++i) {
                        float temp = z[i][c0 + 1];
                        z[i][c0 + 1] = cj * temp - sj * z[i][c0];
                        z[i][c0]     = sj * temp + cj * z[i][c0];
                    }
                }
                d[l - 1] -= p;
                e[l - 1] = g;
            }
        } else {
            // QR
            while (true) {
                int mq = lend;
                if (l != lend) {
                    for (int i = l; i >= lend + 1; --i) {
                        float ei = e[i - 2];
                        float tst = ei * ei;
                        if (tst <= (eps2 * fabsf(d[i - 1])) * fabsf(d[i - 2]) + safmin) { mq = i; break; }
                    }
                }
                if (mq > lend) e[mq - 2] = 0.f;
                float p = d[l - 1];
                if (mq == l) { d[l - 1] = p; l = l - 1; if (l >= lend) continue; break; }
                if (mq == l - 1) {
                    float rt1, rt2, c, s;
                    f_slaev2(d[l - 2], e[l - 2], d[l - 1], &rt1, &rt2, &c, &s);
                    for (int i = 0; i < 3; ++i) {
                        float temp = z[i][l - 1];
                        z[i][l - 1] = c * temp - s * z[i][l - 2];
                        z[i][l - 2] = s * temp + c * z[i][l - 2];
                    }
                    d[l - 2] = rt1; d[l - 1] = rt2; e[l - 2] = 0.f;
                    l -= 2; if (l >= lend) continue; break;
                }
                if (jtot == nmaxit) break;
                jtot++;
                float g = (d[l - 2] - p) / (2.f * e[l - 2]);
                float r = f_slapy2(g, 1.f);
                g = d[mq - 1] - p + e[l - 2] / (g + copysignf(r, g));
                float s = 1.f, c = 1.f; p = 0.f;
                float cw[2], sw[2];
                for (int i = mq; i <= l - 1; ++i) {
                    float f = s * e[i - 1];
                    float b = c * e[i - 1];
                    f_slartg(g, f, &c, &s, &r);
                    if (i != mq) e[i - 2] = r;
                    g = d[i - 1] - p;
                    r = (d[i] - g) * s + 2.f * c * b;
                    p = s * r;
                    d[i - 1] = g + p;
                    g = c * r - b;
                    cw[i - mq] = c; sw[i - mq] = s;
                }
                for (int j = 1; j <= l - mq; ++j) {
                    float cj = cw[j - 1], sj = sw[j - 1];
                    int c0 = mq - 1 + (j - 1);
                    for (int i = 0; i < 3; ++i) {
                        float temp = z[i][c0 + 1];
                        z[i][c0 + 1] = cj * temp - sj * z[i][c0];
                        z[i][c0]     = sj * temp + cj * z[i][c0];
                    }
                }
                d[l - 1] -= p;
                e[l - 2] = g;
            }
        }
        if (iscale) {
            float mul = anorm / sclto;
            for (int i = lsv; i <= lendsv; ++i) d[i - 1] *= mul;
            for (int i = lsv; i <= lendsv - 1; ++i) e[i - 1] *= mul;
        }
        if (jtot >= nmaxit) break;
    }

    // sort ascending (column swaps — no sign change)
    for (int ii = 2; ii <= 3; ++ii) {
        int i = ii - 1, k = i;
        float p = d[i - 1];
        for (int j = ii; j <= 3; ++j) if (d[j - 1] < p) { k = j; p = d[j - 1]; }
        if (k != i) {
            d[k - 1] = d[i - 1]; d[i - 1] = p;
            for (int r = 0; r < 3; ++r) { float t = z[r][i - 1]; z[r][i - 1] = z[r][k - 1]; z[r][k - 1] = t; }
        }
    }
    // sormtr('L','L','N')
    float r0 = z[0][0], r1 = z[1][0], r2 = z[2][0];
    if (tau != 0.f) {
        float sum = r1 + v2 * r2;
        r1 -= tau * sum;
        r2 -= tau * (v2 * sum);
    }
    *ox = r0; *oy = r1; *oz = r2;
}

// ---------------- common ----------------

__device__ __forceinline__ float dot_rn(float ax, float ay, float az,
                                        float bx, float by, float bz) {
    return __fadd_rn(__fadd_rn(__fmul_rn(ax, bx), __fmul_rn(ay, by)), __fmul_rn(az, bz));
}

// Branchless sorted-chain inserts: keys ascending; drops the largest.
__device__ __forceinline__ void chain10(unsigned k[KW], unsigned x) {
    unsigned t = x;
    #pragma unroll
    for (int s = 0; s < KW; ++s) {
        unsigned a = k[s];
        unsigned lo = a < t ? a : t;     // v_min_u32
        unsigned hi = a < t ? t : a;     // v_max_u32
        k[s] = lo; t = hi;
    }
}
__device__ __forceinline__ void chain16(unsigned k[KN], unsigned x) {
    unsigned t = x;
    #pragma unroll
    for (int s = 0; s < KN; ++s) {
        unsigned a = k[s];
        unsigned lo = a < t ? a : t;
        unsigned hi = a < t ? t : a;
        k[s] = lo; t = hi;
    }
}

// ---------------- repack kernel ----------------
__global__ __launch_bounds__(256) void repack_kernel(
    const float* __restrict__ pred, const float* __restrict__ gt,
    float4* __restrict__ p4, float4* __restrict__ g4)
{
    int i = blockIdx.x * 256 + threadIdx.x;       // 0 .. 2*NB*NP-1
    int half = NB * NP;
    const float* src = (i < half) ? pred : gt;
    int k = (i < half) ? i : i - half;
    float x = src[3 * k], y = src[3 * k + 1], z = src[3 * k + 2];
    float4 v = make_float4(x, y, z, dot_rn(x, y, z, x, y, z));
    ((i < half) ? p4 : g4)[k] = v;
}

// ---------------- scan kernel ----------------
// 256 blocks x 512 threads (8 waves). Block = tile-PAIR of 128 queries; each
// lane owns 2 queries (im0 = tp*128+lane, im1 = im0+64). Wave w scans slice
// j = 8t+w via LDS broadcast; each candidate feeds BOTH chains (ILP2).
// Tail distributed: wave w merges+solves queries lq = 16w..16w+15 (lanes
// 4x-duplicated, lane<16 writes). Exact top-16 via 8x10 merge + violation
// detect + rare global rescan. Keys: (d2bits & ~0x7FF) | j, ref-exact d2.
#define KIDX2(s, w, q) (((s) * 8 + (w)) * 128 + (q))

__global__ __launch_bounds__(512) void scan_kernel(
    const float* __restrict__ pred, const float* __restrict__ gt,
    const float4* __restrict__ p4, const float4* __restrict__ g4,
    float4* __restrict__ nP4, float4* __restrict__ nG4, double* __restrict__ acc)
{
    __shared__ unsigned smem[16384];                  // 64 KB
    float4* sHome  = (float4*)smem;                   // [2048] first 32 KB
    float4* sOther = (float4*)smem + NP;              // [2048] second 32 KB
    unsigned* kbuf = smem;                            // post-scan: [10][8][128] = 40 KB
    float* mbuf = (float*)(smem + KW * 8 * 128);      // [8][128] = 4 KB

    int bi = blockIdx.x;
    bool predHome = bi < NB * 16;
    int lb = predHome ? bi : bi - NB * 16;
    int b = lb >> 4;
    int tp = lb & 15;                 // tile-pair (128 queries)
    int tid  = threadIdx.x;
    int wave = tid >> 6;
    int lane = tid & 63;

    const float*  home  = (predHome ? pred : gt) + (size_t)b * NP * 3;
    const float4* h4g   = (predHome ? p4 : g4) + (size_t)b * NP;
    const float4* o4g   = (predHome ? g4 : p4) + (size_t)b * NP;

    for (int t = tid; t < NP; t += 512) {
        sHome[t]  = h4g[t];
        sOther[t] = o4g[t];
    }
    __syncthreads();

    int im0 = tp * 128 + lane;
    int im1 = im0 + 64;
    float4 qa = sHome[im0];
    float4 qb = sHome[im1];

    unsigned keysA[KW], keysB[KW];
    #pragma unroll
    for (int s = 0; s < KW; ++s) { keysA[s] = 0x7F800000u | (unsigned)s; keysB[s] = keysA[s]; }

    float minvA = 1e30f, minvB = 1e30f;

    for (int t = 0; t < NP / 8; ++t) {
        int jj = (t << 3) | wave;
        float4 h = sHome[jj];                                  // broadcast b128
        float da = dot_rn(qa.x, qa.y, qa.z, h.x, h.y, h.z);
        float d2a = __fsub_rn(__fadd_rn(qa.w, h.w), __fmul_rn(2.f, da));
        chain10(keysA, (__float_as_uint(d2a) & 0xFFFFF800u) | (unsigned)jj);
        float db = dot_rn(qb.x, qb.y, qb.z, h.x, h.y, h.z);
        float d2b = __fsub_rn(__fadd_rn(qb.w, h.w), __fmul_rn(2.f, db));
        chain10(keysB, (__float_as_uint(d2b) & 0xFFFFF800u) | (unsigned)jj);
        float4 o = sOther[jj];                                 // broadcast b128
        float ea = qa.x - o.x, fa = qa.y - o.y, ga = qa.z - o.z;
        minvA = fminf(minvA, fmaf(ea, ea, fmaf(fa, fa, ga * ga)));
        float eb = qb.x - o.x, fb = qb.y - o.y, gb = qb.z - o.z;
        minvB = fminf(minvB, fmaf(eb, eb, fmaf(fb, fb, gb * gb)));
    }
    __syncthreads();   // all staging reads done before kbuf aliasing writes

    // publish per-wave sorted top-10s + chamfer partial mins
    #pragma unroll
    for (int s = 0; s < KW; ++s) {
        kbuf[KIDX2(s, wave, lane)]      = keysA[s];
        kbuf[KIDX2(s, wave, lane + 64)] = keysB[s];
    }
    mbuf[wave * 128 + lane]      = minvA;
    mbuf[wave * 128 + lane + 64] = minvB;
    __syncthreads();

    // ---- distributed tail: wave w owns queries lq = 16w .. 16w+15 ----
    int lq = wave * 16 + (lane & 15);    // lanes 4x-duplicated; lane<16 writes
    bool writer = lane < 16;

    // merge 8x10 -> sorted top-16 (start from slice 0's sorted 10)
    unsigned k16[KN];
    #pragma unroll
    for (int s = 0; s < KW; ++s) k16[s] = kbuf[KIDX2(s, 0, lq)];
    #pragma unroll
    for (int s = KW; s < KN; ++s) k16[s] = 0x7F800000u | (unsigned)s;  // seeds (> any real)
    for (int w = 1; w < 8; ++w) {
        #pragma unroll
        for (int s = 0; s < KW; ++s) chain16(k16, kbuf[KIDX2(s, w, lq)]);
    }
    float minv = mbuf[lq];
    #pragma unroll
    for (int w = 1; w < 8; ++w) minv = fminf(minv, mbuf[w * 128 + lq]);

    // violation detect: slice may hide a top-16 member iff its 10th-best
    // (sorted slot 9) < pool 16th (k16[15]). Exact repair below.
    unsigned flags = 0;
    #pragma unroll
    for (int w = 0; w < 8; ++w)
        flags |= (kbuf[KIDX2(KW - 1, w, lq)] < k16[15]) ? (1u << w) : 0u;

    if (__any(flags != 0)) {                 // ~0.03 expected events per LAUNCH
        #pragma unroll
        for (int s = 0; s < KN; ++s)
            k16[s] = flags ? (0x7F800000u | (unsigned)s) : k16[s];   // reinit flagged lanes
        for (int w = 0; w < 8; ++w) {
            #pragma unroll
            for (int s = 0; s < KW; ++s) {
                unsigned kk = kbuf[KIDX2(s, w, lq)];
                bool use = (flags != 0) && !((flags >> w) & 1);
                chain16(k16, use ? kk : 0xFFFFFFFFu);          // inf = no-op
            }
        }
        float4 qv = sHome ? make_float4(0,0,0,0) : make_float4(0,0,0,0); // (unused)
        // query coords for rescan (sHome is overwritten): from global
        float4 qg = h4g[tp * 128 + lq];
        for (int w = 0; w < 8; ++w) {
            if (__any((flags >> w) & 1)) {
                bool actw = ((flags >> w) & 1) != 0;
                for (int t = 0; t < NP / 8; ++t) {
                    int jj = (t << 3) | w;
                    float4 h = h4g[jj];                        // global, L2-hot
                    float dj = dot_rn(qg.x, qg.y, qg.z, h.x, h.y, h.z);
                    float d2 = __fsub_rn(__fadd_rn(qg.w, h.w), __fmul_rn(2.f, dj));
                    unsigned key = (__float_as_uint(d2) & 0xFFFFF800u) | (unsigned)jj;
                    chain16(k16, actw ? key : 0xFFFFFFFFu);
                }
            }
        }
    }

    // repulsion: k16 sorted ascending, slot 0 = self (d2=0) -> slots 1..4
    float rep = 0.0f;
    if (predHome) {
        #pragma unroll
        for (int r = 1; r <= 4; ++r) {
            float d2 = __uint_as_float(k16[r] & 0xFFFFF800u);
            float dd = sqrtf(fmaxf(d2, 1e-12f));
            rep += fmaxf(0.02f - dd, 0.0f);
        }
    }

    // covariance over the 16-NN: gather by index from global (L2-hot),
    // neighbors held in registers (unrolled constant indices).
    float nbx[KN], nby[KN], nbz[KN];
    float sx = 0.f, sy = 0.f, sz = 0.f;
    #pragma unroll
    for (int s = 0; s < KN; ++s) {
        const float* hp = home + 3 * (size_t)(k16[s] & 0x7FFu);
        nbx[s] = hp[0]; nby[s] = hp[1]; nbz[s] = hp[2];
        sx += nbx[s]; sy += nby[s]; sz += nbz[s];
    }
    float mx = sx * (1.0f / KN), my = sy * (1.0f / KN), mz = sz * (1.0f / KN);
    float cxx = 0.f, cxy = 0.f, cxz = 0.f, cyy = 0.f, cyz = 0.f, czz = 0.f;
    #pragma unroll
    for (int s = 0; s < KN; ++s) {
        float ax = nbx[s] - mx, ay = nby[s] - my, az = nbz[s] - mz;
        cxx += ax * ax; cxy += ax * ay; cxz += ax * az;
        cyy += ay * ay; cyz += ay * az; czz += az * az;
    }
    cxx *= (1.f / KN); cxy *= (1.f / KN); cxz *= (1.f / KN);
    cyy *= (1.f / KN); cyz *= (1.f / KN); czz *= (1.f / KN);

    // normal via faithful ssyevd emulation
    float nx, ny, nz;
    ssyevd3_evec0(cxx, cxy, cxz, cyy, cyz, czz, &nx, &ny, &nz);

    if (writer) {
        int gi = b * NP + tp * 128 + lq;
        (predHome ? nP4 : nG4)[gi] = make_float4(nx, ny, nz, 0.f);
    }

    double part = writer ? ((double)minv * (1.0 / (NB * NP))
                          + (double)rep  * (0.1 / (NB * NP * 4))) : 0.0;

    #pragma unroll
    for (int off = 32; off > 0; off >>= 1) part += __shfl_down(part, off);
    if (lane == 0) atomicAdd(acc, part);
}

// ---------------------------------------------------------------------------
// Fused normal-dot + finalize: single block, runs after scan (stream order).
__global__ __launch_bounds__(1024) void dotfin_kernel(
    const float4* __restrict__ nP4, const float4* __restrict__ nG4,
    const double* __restrict__ acc, float* __restrict__ out)
{
    int tid = threadIdx.x;
    float s = 0.f;
    for (int i = tid; i < NB * NP; i += 1024) {
        float4 a = nP4[i], c = nG4[i];
        s += a.x * c.x + a.y * c.y + a.z * c.z;
    }
    double part = (double)s;
    #pragma unroll
    for (int off = 32; off > 0; off >>= 1) part += __shfl_down(part, off);
    __shared__ double w[16];
    if ((tid & 63) == 0) w[tid >> 6] = part;
    __syncthreads();
    if (tid == 0) {
        double t = 0.0;
        for (int k = 0; k < 16; ++k) t += w[k];
        out[0] = (float)(acc[0] - t * (0.01 / (NB * NP)) + 0.01);
    }
}

// ---------------------------------------------------------------------------
extern "C" void kernel_launch(void* const* d_in, const int* in_sizes, int n_in,
                              void* d_out, int out_size, void* d_ws, size_t ws_size,
                              hipStream_t stream)
{
    const float* pred = (const float*)d_in[0];
    const float* gt   = (const float*)d_in[1];

    // ws layout: acc(64) | p4 (262144) | g4 (262144) | nP4 (262144) | nG4 (262144)
    char* base = (char*)d_ws;
    double* acc = (double*)base;
    float4* p4  = (float4*)(base + 64);
    float4* g4  = p4 + (size_t)NB * NP;
    float4* nP4 = g4 + (size_t)NB * NP;
    float4* nG4 = nP4 + (size_t)NB * NP;

    hipMemsetAsync(d_ws, 0, 64, stream);
    repack_kernel<<<dim3(2 * NB * NP / 256), dim3(256), 0, stream>>>(pred, gt, p4, g4);
    scan_kernel<<<dim3(NB * 16 * 2), dim3(512), 0, stream>>>(pred, gt, p4, g4, nP4, nG4, acc);
    dotfin_kernel<<<dim3(1), dim3(1024), 0, stream>>>(nP4, nG4, acc, (float*)d_out);
}